// Round 9
// baseline (132.006 us; speedup 1.0000x reference)
//
#include <hip/hip_runtime.h>

#define NEGV -1e30f

// Problem constants (fixed by setup_inputs)
constexpr int Bn = 8, Ci = 64, Hn = 64, Wn = 64, Co = 64;
constexpr int WT_ELEMS = Ci * 9 * Co;   // 36864
constexpr int HW = Hn * Wn;

// ---- pre-pass: wT[ci][k][co] = wt[co][ci][k] (147456 B in d_ws) ----
__global__ __launch_bounds__(256)
void wtrans_kernel(const float* __restrict__ wt, float* __restrict__ wT) {
    int idx = blockIdx.x * 256 + threadIdx.x;
    if (idx < WT_ELEMS) {
        int co = idx & 63;
        int k  = (idx >> 6) % 9;
        int ci = idx / 576;
        wT[idx] = wt[((size_t)co * Ci + ci) * 9 + k];
    }
}

__device__ __forceinline__ float vmax3(float a, float b, float c) {
    float d;
    asm("v_max3_f32 %0, %1, %2, %3" : "=v"(d) : "v"(a), "v"(b), "v"(c));
    return d;
}

// Window row (cols w0-1 .. w0+8) via UNIFORM-address VMEM: all 64 lanes read
// the same address -> one L1 line transaction, broadcast into VGPRs.
// f4@w0 and f4@w0+4 are 16B-aligned (w0 % 8 == 0, rows 256B-aligned);
// boundary scalars are clamped loads + one uniform cndmask each.
__device__ __forceinline__ void rowload(float* o, const float* __restrict__ p,
                                        int w0, bool eL, bool eR) {
    float4 a = *reinterpret_cast<const float4*>(p + w0);
    float4 c = *reinterpret_cast<const float4*>(p + w0 + 4);
    float l = p[w0 - 1 + (eL ? 1 : 0)];
    float r = p[w0 + 8 - (eR ? 1 : 0)];
    o[0] = eL ? NEGV : l;
    o[1] = a.x; o[2] = a.y; o[3] = a.z; o[4] = a.w;
    o[5] = c.x; o[6] = c.y; o[7] = c.z; o[8] = c.w;
    o[9] = eR ? NEGV : r;
}

// pure core: per px 9 v_add + 4 v_max3 + 1 v_max
__device__ __forceinline__ void compute8(float* acc, const float* xu,
                                         const float* xc, const float* xd,
                                         const float* wv) {
#pragma unroll
    for (int j = 0; j < 8; j++) {
        float t0 = xu[j] + wv[0], t1 = xu[j + 1] + wv[1], t2 = xu[j + 2] + wv[2];
        float t3 = xc[j] + wv[3], t4 = xc[j + 1] + wv[4], t5 = xc[j + 2] + wv[5];
        float t6 = xd[j] + wv[6], t7 = xd[j + 1] + wv[7], t8 = xd[j + 2] + wv[8];
        float m0 = vmax3(t0, t1, t2);
        float m1 = vmax3(t3, t4, t5);
        float m2 = vmax3(t6, t7, t8);
        acc[j] = vmax3(acc[j], m0, m1);
        acc[j] = fmaxf(acc[j], m2);
    }
}

// RE: 0 = interior row, 1 = top (h==0, up row is compile-time NEGV),
// 2 = bottom (h==Hn-1, down row compile-time NEGV).
template<int RE>
__device__ __forceinline__ void body(float* acc, const float* __restrict__ pc,
                                     const float* __restrict__ wp,
                                     int w0, bool eL, bool eR) {
    float wv[9];
#pragma unroll
    for (int k = 0; k < 9; k++) wv[k] = wp[k * 64];   // coalesced, imm k*256B

    float xu[10], xc[10], xd[10];
    rowload(xc, pc, w0, eL, eR);
    if (RE != 1) rowload(xu, pc - Wn, w0, eL, eR);
    else {
#pragma unroll
        for (int c = 0; c < 10; c++) xu[c] = NEGV;
    }
    if (RE != 2) rowload(xd, pc + Wn, w0, eL, eR);
    else {
#pragma unroll
        for (int c = 0; c < 10; c++) xd[c] = NEGV;
    }
    compute8(acc, xu, xc, xd, wv);
}

template<int RE>
__device__ __forceinline__ void run_wave(const float* __restrict__ x,
                                         const float* __restrict__ wT,
                                         float* __restrict__ out,
                                         int b, int h, int w0, int lane) {
    const bool eL = (w0 == 0);
    const bool eR = (w0 == Wn - 8);

    const float* pc = x + (((size_t)b * Ci) * Hn + h) * Wn;   // center row, ci=0
    const float* wp = wT + lane;                              // per-lane weights

    float acc[8];
#pragma unroll
    for (int j = 0; j < 8; j++) acc[j] = NEGV;

#pragma unroll 1
    for (int ci = 0; ci < Ci; ci += 2) {
        body<RE>(acc, pc, wp, w0, eL, eR);  pc += HW;  wp += 576;
        body<RE>(acc, pc, wp, w0, eL, eR);  pc += HW;  wp += 576;
    }

    // lane holds 8 consecutive px of its co plane -> two dwordx4 stores
    float* po = out + (((size_t)b * Co + lane) * Hn + h) * Wn + w0;
    *reinterpret_cast<float4*>(po)     = make_float4(acc[0], acc[1], acc[2], acc[3]);
    *reinterpret_cast<float4*>(po + 4) = make_float4(acc[4], acc[5], acc[6], acc[7]);
}

// lane = co (64 lanes = all output channels); wave = 8 px of one output row;
// block = (b, h, half-row) = 4 waves, 1024 blocks = 4/CU = 16 waves/CU.
// NO LDS, NO barriers, NO staging, NO s_loads in the loop: per ci just
// 12 uniform x VMEM + 9 coalesced weight VMEM + ~124 VALU.
__global__ __launch_bounds__(256, 4)
void maxconv_main(const float* __restrict__ x, const float* __restrict__ wT,
                  float* __restrict__ out) {
    const int lane = threadIdx.x & 63;
    const int wvid = threadIdx.x >> 6;              // 0..3

    // XCD swizzle: id%8 = b -> each XCD owns one batch image (1 MB x, L2-hot)
    const int lg   = ((blockIdx.x & 7) << 7) | (blockIdx.x >> 3);
    const int b    = lg >> 7;
    const int rem  = lg & 127;
    const int h    = rem >> 1;
    const int half = rem & 1;
    // readfirstlane: provably wave-uniform window base
    const int w0 = __builtin_amdgcn_readfirstlane(half * 32 + wvid * 8);

    if (h == 0)            run_wave<1>(x, wT, out, b, h, w0, lane);
    else if (h == Hn - 1)  run_wave<2>(x, wT, out, b, h, w0, lane);
    else                   run_wave<0>(x, wT, out, b, h, w0, lane);
}

extern "C" void kernel_launch(void* const* d_in, const int* in_sizes, int n_in,
                              void* d_out, int out_size, void* d_ws, size_t ws_size,
                              hipStream_t stream) {
    const float* x  = (const float*)d_in[0];
    const float* wt = (const float*)d_in[1];
    float* out = (float*)d_out;
    float* wT  = (float*)d_ws;   // 147456 B

    wtrans_kernel<<<(WT_ELEMS + 255) / 256, 256, 0, stream>>>(wt, wT);

    maxconv_main<<<1024, 256, 0, stream>>>(x, wT, out);
}

// Round 10
// 118.508 us; speedup vs baseline: 1.1139x; 1.1139x over previous
//
#include <hip/hip_runtime.h>

#define NEGV -1e30f

// Problem constants (fixed by setup_inputs)
constexpr int Bn = 8, Ci = 64, Hn = 64, Wn = 64, Co = 64;
constexpr int WT_ELEMS = Ci * 9 * Co;   // 36864
constexpr int HW = Hn * Wn;

// ---- pre-pass: wT[ci][k][co] = wt[co][ci][k] (147456 B in d_ws) ----
__global__ __launch_bounds__(256)
void wtrans_kernel(const float* __restrict__ wt, float* __restrict__ wT) {
    int idx = blockIdx.x * 256 + threadIdx.x;
    if (idx < WT_ELEMS) {
        int co = idx & 63;
        int k  = (idx >> 6) % 9;
        int ci = idx / 576;
        wT[idx] = wt[((size_t)co * Ci + ci) * 9 + k];
    }
}

__device__ __forceinline__ float vmax3(float a, float b, float c) {
    float d;
    asm("v_max3_f32 %0, %1, %2, %3" : "=v"(d) : "v"(a), "v"(b), "v"(c));
    return d;
}

// uniform LDS window read: 10 floats = b128 + b128 + b64 (16B-aligned base)
__device__ __forceinline__ void read10(float* o, const float* __restrict__ p) {
    float4 a = *reinterpret_cast<const float4*>(p);
    float4 b = *reinterpret_cast<const float4*>(p + 4);
    float2 c = *reinterpret_cast<const float2*>(p + 8);
    o[0] = a.x; o[1] = a.y; o[2] = a.z; o[3] = a.w;
    o[4] = b.x; o[5] = b.y; o[6] = b.z; o[7] = b.w;
    o[8] = c.x; o[9] = c.y;
}

__device__ __forceinline__ void issue_x(float* xu, float* xc, float* xd,
                                        const float* __restrict__ xq) {
    read10(xu, xq);
    read10(xc, xq + 40);
    read10(xd, xq + 80);
}

__device__ __forceinline__ void issue_w(float* wv, const float* __restrict__ wq) {
#pragma unroll
    for (int k = 0; k < 9; k++) wv[k] = wq[k * 64];   // coalesced, imm k*256B
}

// pure core: per px 9 v_add + 4 v_max3 + 1 v_max
__device__ __forceinline__ void compute8(float* acc, const float* xu,
                                         const float* xc, const float* xd,
                                         const float* wv) {
#pragma unroll
    for (int j = 0; j < 8; j++) {
        float t0 = xu[j] + wv[0], t1 = xu[j + 1] + wv[1], t2 = xu[j + 2] + wv[2];
        float t3 = xc[j] + wv[3], t4 = xc[j + 1] + wv[4], t5 = xc[j + 2] + wv[5];
        float t6 = xd[j] + wv[6], t7 = xd[j + 1] + wv[7], t8 = xd[j + 2] + wv[8];
        float m0 = vmax3(t0, t1, t2);
        float m1 = vmax3(t3, t4, t5);
        float m2 = vmax3(t6, t7, t8);
        acc[j] = vmax3(acc[j], m0, m1);
        acc[j] = fmaxf(acc[j], m2);
    }
}

// R8 structure (lane = co, wave = 8 px of one row, block = half-row, x staged
// in LDS once, weights coalesced VMEM) + explicit 2-deep software pipeline:
// loads for ci are issued one full compute-phase before use (ping-pong A/B),
// so LDS (~120cyc) and L2 weight (~300cyc) latency is covered and the
// compiler's in-order lgkmcnt/vmcnt waits are ~free. No sched_barrier pins.
__global__ __launch_bounds__(256, 4)
void maxconv_main(const float* __restrict__ x, const float* __restrict__ wT,
                  float* __restrict__ out) {
    __shared__ __align__(16) float xs[Ci * 120];   // [ci][3 rows][40] = 30720 B

    const int tid  = threadIdx.x;
    const int lane = tid & 63;
    const int wvid = tid >> 6;                      // 0..3

    // XCD chunking: hw id%8 selects XCD; logical chunk = one batch image b.
    const int lg   = ((blockIdx.x & 7) << 7) | (blockIdx.x >> 3);
    const int b    = lg >> 7;
    const int rem  = lg & 127;
    const int h    = rem >> 1;
    const int half = rem & 1;
    const int w0h  = half << 5;                     // 0 or 32

    // ---- upfront staging (identical to R8, verified): threads {0..101} do
    // ci 0..31, {128..229} ci 32..63; invalid coords write NEGV.
    {
        const int st     = (tid < 128) ? tid : tid - 128;
        const int cibase = (tid < 128) ? 0 : 32;
        if (st < 102) {
            const int r    = st / 34;
            const int s    = st - r * 34;
            const int grow = h - 1 + r;
            const int gcol = w0h - 1 + s;
            const bool valid = (grow >= 0) && (grow < Hn) && (gcol >= 0) && (gcol < Wn);
            const int cg   = valid ? grow : 0;
            const int cc   = valid ? gcol : 0;
            const float* gp = x + (((size_t)b * Ci + cibase) * Hn + cg) * Wn + cc;
            const int dst  = r * 40 + s;
#pragma unroll 1
            for (int c8 = 0; c8 < 32; c8 += 8) {
                float v[8];
#pragma unroll
                for (int i = 0; i < 8; i++)
                    v[i] = valid ? gp[(size_t)(c8 + i) * HW] : NEGV;
#pragma unroll
                for (int i = 0; i < 8; i++)
                    xs[(cibase + c8 + i) * 120 + dst] = v[i];
            }
        }
    }
    __syncthreads();   // the only block-wide sync

    const int woff = wvid * 8;          // this wave's slot base (16B-aligned)

    const float* wq = wT + lane;        // weight stream (advances 576/issue)
    const float* xq = xs + woff;        // LDS stream (advances 120/issue)

    float acc[8];
#pragma unroll
    for (int j = 0; j < 8; j++) acc[j] = NEGV;

    float wvA[9], wvB[9];
    float xuA[10], xcA[10], xdA[10];
    float xuB[10], xcB[10], xdB[10];

    // prologue: ci=0 and ci=1 in flight
    issue_w(wvA, wq);  issue_x(xuA, xcA, xdA, xq);  wq += 576;  xq += 120;
    issue_w(wvB, wq);  issue_x(xuB, xcB, xdB, xq);  wq += 576;  xq += 120;

#pragma unroll 1
    for (int ci = 0; ci < Ci - 4; ci += 2) {
        compute8(acc, xuA, xcA, xdA, wvA);                       // ci
        issue_w(wvA, wq);  issue_x(xuA, xcA, xdA, xq);           // ci+2
        wq += 576;  xq += 120;
        compute8(acc, xuB, xcB, xdB, wvB);                       // ci+1
        issue_w(wvB, wq);  issue_x(xuB, xcB, xdB, xq);           // ci+3
        wq += 576;  xq += 120;
    }
    // epilogue: ci = 60..63 (issues taper off)
    compute8(acc, xuA, xcA, xdA, wvA);                           // 60
    issue_w(wvA, wq);  issue_x(xuA, xcA, xdA, xq);               // 62
    compute8(acc, xuB, xcB, xdB, wvB);                           // 61
    issue_w(wvB, wq + 576);  issue_x(xuB, xcB, xdB, xq + 120);   // 63
    compute8(acc, xuA, xcA, xdA, wvA);                           // 62
    compute8(acc, xuB, xcB, xdB, wvB);                           // 63

    // lane holds 8 consecutive px of its co plane -> two dwordx4 stores
    float* po = out + (((size_t)b * Co + lane) * Hn + h) * Wn + w0h + woff;
    *reinterpret_cast<float4*>(po)     = make_float4(acc[0], acc[1], acc[2], acc[3]);
    *reinterpret_cast<float4*>(po + 4) = make_float4(acc[4], acc[5], acc[6], acc[7]);
}

extern "C" void kernel_launch(void* const* d_in, const int* in_sizes, int n_in,
                              void* d_out, int out_size, void* d_ws, size_t ws_size,
                              hipStream_t stream) {
    const float* x  = (const float*)d_in[0];
    const float* wt = (const float*)d_in[1];
    float* out = (float*)d_out;
    float* wT  = (float*)d_ws;   // 147456 B

    wtrans_kernel<<<(WT_ELEMS + 255) / 256, 256, 0, stream>>>(wt, wT);

    // 1024 blocks = 4 blocks/CU = 16 waves/CU; LDS 30 KB x 4 = 120 KB/CU
    maxconv_main<<<1024, 256, 0, stream>>>(x, wT, out);
}